// Round 14
// baseline (7800.467 us; speedup 1.0000x reference)
//
#include <hip/hip_runtime.h>
#include <hip/hip_bf16.h>

typedef __attribute__((ext_vector_type(4))) int   i32x4;
typedef __attribute__((ext_vector_type(4))) float f32x4;
typedef __attribute__((ext_vector_type(4))) short s16x4;
typedef __attribute__((ext_vector_type(8))) short s16x8;

#define B_  32
#define T_  512
#define F_  128
#define H_  2048
#define V_  32
#define NBLK_ 64

static __device__ __forceinline__ int clampi16(int v) {
  v = v < -32768 ? -32768 : v;
  return v > 32767 ? 32767 : v;
}
static __device__ __forceinline__ short f2bf(float f) {
  union { __hip_bfloat16 b; short s; } u; u.b = __float2bfloat16(f); return u.s;
}

// XLA-CPU tanh under legacy fast-math: Eigen/XLA rational approximation with
// FMA-contracted Horner chains. (R10-validated bit-level grading target.)
static __device__ __forceinline__ float xla_tanh_fma(float x) {
#pragma clang fp contract(off)
  const float kClamp = 7.90531110763549805f;
  float xc = fminf(fmaxf(x, -kClamp), kClamp);
  float x2 = xc * xc;
  float a;
  a = -2.76076847742355e-16f;                          // alpha_13
  a = __builtin_fmaf(a, x2, 2.00018790482477e-13f);    // alpha_11
  a = __builtin_fmaf(a, x2, -8.60467152213735e-11f);   // alpha_9
  a = __builtin_fmaf(a, x2, 5.12229709037114e-08f);    // alpha_7
  a = __builtin_fmaf(a, x2, 1.48572235717979e-05f);    // alpha_5
  a = __builtin_fmaf(a, x2, 6.37261928875436e-04f);    // alpha_3
  a = __builtin_fmaf(a, x2, 4.89352455891786e-03f);    // alpha_1
  float num = xc * a;
  float b;
  b = 1.19825839466702e-06f;                           // beta_6
  b = __builtin_fmaf(b, x2, 1.18534705686654e-04f);    // beta_4
  b = __builtin_fmaf(b, x2, 2.26843463243900e-03f);    // beta_2
  b = __builtin_fmaf(b, x2, 4.89352518554385e-03f);    // beta_0
  float r = num / b;                                   // IEEE div
  return (fabsf(x) < 0.0004f) ? x : r;
}

// ---------------- Phase 0: pack weights to bf16 (exact: |w|<=7) ----------------
__global__ __launch_bounds__(256) void pack_k(const int* __restrict__ Wr4,
                                              const int* __restrict__ Wi4,
                                              const float* __restrict__ Wo,
                                              short* __restrict__ WrB,
                                              short* __restrict__ WiB,
                                              short* __restrict__ WoB) {
  const int idx = blockIdx.x * 256 + threadIdx.x;  // grid 4096 -> 1,048,576
  {
    i32x4 v = *(const i32x4*)(Wr4 + (size_t)idx * 4);
    s16x4 o;
#pragma unroll
    for (int r = 0; r < 4; ++r) o[r] = f2bf((float)v[r]);
    *(s16x4*)(WrB + (size_t)idx * 4) = o;
  }
  if (idx < (H_ * F_ / 4)) {
    i32x4 v = *(const i32x4*)(Wi4 + (size_t)idx * 4);
    s16x4 o;
#pragma unroll
    for (int r = 0; r < 4; ++r) o[r] = f2bf((float)v[r]);
    *(s16x4*)(WiB + (size_t)idx * 4) = o;
  }
  if (idx < (V_ * H_ / 4)) {
    f32x4 f = *(const f32x4*)(Wo + (size_t)idx * 4);
    s16x4 o;
#pragma unroll
    for (int r = 0; r < 4; ++r) o[r] = f2bf(f[r]);
    *(s16x4*)(WoB + (size_t)idx * 4) = o;
  }
}

// ---------------- Phase 1: Oin[t][j][b] = clip(u_int @ Wi^T, int16) ----------------
__global__ __launch_bounds__(256) void in_gemm(const float* __restrict__ x,
                                               const short* __restrict__ WiB,
                                               short* __restrict__ Oin) {
  const int t  = blockIdx.x;
  const int jt = blockIdx.y;
  const int tid = threadIdx.x;
  const int l = tid & 63, w = tid >> 6;
  const int mh = w & 1, q = w >> 1;
  const int lr = l & 15, lc = l >> 4;
  const int brow = mh * 16 + lr;

  s16x8 af[4];
  const float* xp = x + ((size_t)brow * T_ + t) * F_;
#pragma unroll
  for (int kk = 0; kk < 4; ++kk) {
    f32x4 f0 = *(const f32x4*)(xp + kk * 32 + lc * 8);
    f32x4 f1 = *(const f32x4*)(xp + kk * 32 + lc * 8 + 4);
    s16x8 a;
#pragma unroll
    for (int c = 0; c < 4; ++c) a[c]     = f2bf(rintf(f0[c] * 7.0f));
#pragma unroll
    for (int c = 0; c < 4; ++c) a[4 + c] = f2bf(rintf(f1[c] * 7.0f));
    af[kk] = a;
  }
#pragma unroll
  for (int s = 0; s < 4; ++s) {
    const int j = jt * 128 + q * 64 + s * 16 + lr;
    f32x4 acc = {0.f, 0.f, 0.f, 0.f};
#pragma unroll
    for (int kk = 0; kk < 4; ++kk) {
      s16x8 b = *(const s16x8*)(WiB + (size_t)j * F_ + kk * 32 + lc * 8);
      acc = __builtin_amdgcn_mfma_f32_16x16x32_bf16(af[kk], b, acc, 0, 0, 0);
    }
    short* op = Oin + ((size_t)t * H_ + j) * B_ + mh * 16 + lc * 4;
    s16x4 ov;
#pragma unroll
    for (int r = 0; r < 4; ++r) ov[r] = (short)clampi16((int)acc[r]);
    *(s16x4*)op = ov;
  }
}

// ---------------- Phase 2: persistent recurrence, striped grid barrier ----------------
// R14 change vs R13: the single barrier counter (64 serialized RELEASE RMWs on
// one line ~= the whole 15 us/step) is STRIPED across 8 cache lines
// (block bid&7 -> line, 128 B apart). Arrival RMWs serialize only 8-deep per
// line, in parallel across lines. Poll = sum of 8 relaxed loads (monotonic:
// observed-sum >= target implies true-sum >= target). Numerics untouched.
__global__ __launch_bounds__(256, 1) void recur_pers(const short* __restrict__ WrB,
                                                     const short* __restrict__ Oin,
                                                     const float* __restrict__ Sres,
                                                     const float* __restrict__ Sin,
                                                     short* __restrict__ Hb,
                                                     short* __restrict__ Hs,
                                                     int* __restrict__ barcnt) {
#pragma clang fp contract(off)
  const int tid = threadIdx.x;
  const int l = tid & 63, w = tid >> 6;
  const int mh = w & 1, nh = w >> 1;
  const int lr = l & 15, lc = l >> 4;
  const int jl = blockIdx.x * 32 + nh * 16 + lr;   // unit (MFMA col)
  const int b0 = mh * 16;

  const float RC49 = 1.0f / 49.0f;
  const float sres = Sres[jl] * RC49;    // fast-math: x/49 -> x*(1/49)
  const float sinl = Sin[jl]  * RC49;

  // Preload W row fragments into regs (lands in unified AGPR file) and pin.
  const short* wrow = WrB + (size_t)jl * H_ + lc * 8;
  s16x8 wreg[64];
#pragma unroll
  for (int kk = 0; kk < 64; ++kk) {
    wreg[kk] = *(const s16x8*)(wrow + kk * 32);
    asm volatile("" : "+v"(wreg[kk]));
  }

  for (int t = 0; t < T_; ++t) {
    const short* hin  = Hb + (t & 1) * (B_ * H_);
    short*       hout = Hb + ((t + 1) & 1) * (B_ * H_);
    const short* hrow = hin + (size_t)(b0 + lr) * H_ + lc * 8;

    const s16x4 oin = *(const s16x4*)(Oin + ((size_t)t * H_ + jl) * B_ + b0 + lc * 4);

    f32x4 acc0 = {0.f, 0.f, 0.f, 0.f}, acc1 = {0.f, 0.f, 0.f, 0.f};
#pragma unroll
    for (int kk = 0; kk < 64; kk += 2) {             // FULL unroll: kk constant
      s16x8 a0 = *(const s16x8*)(hrow + kk * 32);
      s16x8 a1 = *(const s16x8*)(hrow + kk * 32 + 32);
      acc0 = __builtin_amdgcn_mfma_f32_16x16x32_bf16(a0, wreg[kk],     acc0, 0, 0, 0);
      acc1 = __builtin_amdgcn_mfma_f32_16x16x32_bf16(a1, wreg[kk + 1], acc1, 0, 0, 0);
    }

#pragma unroll
    for (int r = 0; r < 4; ++r) {
      const int b = b0 + lc * 4 + r;
      const float resf = acc0[r] + acc1[r];          // exact integer in f32
      const int   res  = clampi16((int)resf);
      const float t2   = (float)oin[r] * sinl;
      const float z    = __builtin_fmaf((float)res, sres, t2);
      const float h    = xla_tanh_fma(z);
      const float hc   = fminf(fmaxf(h, -1.0f), 1.0f);
      Hs[((size_t)b * T_ + t) * H_ + jl] = f2bf(h);
      hout[(size_t)b * H_ + jl] = f2bf(rintf(hc * 7.0f));
    }

    if (t != T_ - 1) {
      __syncthreads();   // block's stores drained (waitcnt) before arrival
      if (tid == 0) {
        // arrival on this block's stripe: RELEASE add (does the L2 writeback)
        __hip_atomic_fetch_add(&barcnt[(blockIdx.x & 7) * 32], 1,
                               __ATOMIC_RELEASE, __HIP_MEMORY_SCOPE_AGENT);
        const int target = NBLK_ * (t + 1);
        for (;;) {
          int s = 0;
#pragma unroll
          for (int i = 0; i < 8; ++i)
            s += __hip_atomic_load(&barcnt[i * 32], __ATOMIC_RELAXED,
                                   __HIP_MEMORY_SCOPE_AGENT);
          if (s >= target) break;
          __builtin_amdgcn_s_sleep(1);
        }
        // single acquire: invalidate stale lines once, then proceed
        __builtin_amdgcn_fence(__ATOMIC_ACQUIRE, "agent");
      }
      __syncthreads();   // fan out
    }
  }
}

// ---------------- Phase 3: out(f32) = Hs(bf16) @ Wo(bf16)^T + bias ----------------
__global__ __launch_bounds__(256) void out_gemm(const unsigned short* __restrict__ Hs,
                                                const unsigned short* __restrict__ WoB,
                                                const float* __restrict__ bias,
                                                float* __restrict__ out) {
  const int tid = threadIdx.x;
  const int l = tid & 63, w = tid >> 6;
  const int m0 = blockIdx.x * 64 + w * 16;
  const int lr = l & 15, lc = l >> 4;

  f32x4 acc0 = {0.f, 0.f, 0.f, 0.f}, acc1 = {0.f, 0.f, 0.f, 0.f};
  const unsigned short* arow = Hs  + (size_t)(m0 + lr) * H_ + lc * 8;
  const unsigned short* bp0  = WoB + (size_t)lr * H_        + lc * 8;
  const unsigned short* bp1  = WoB + (size_t)(16 + lr) * H_ + lc * 8;
#pragma unroll 8
  for (int kk = 0; kk < 64; ++kk) {
    s16x8 a  = *(const s16x8*)(arow + kk * 32);
    s16x8 b0 = *(const s16x8*)(bp0  + kk * 32);
    s16x8 b1 = *(const s16x8*)(bp1  + kk * 32);
    acc0 = __builtin_amdgcn_mfma_f32_16x16x32_bf16(a, b0, acc0, 0, 0, 0);
    acc1 = __builtin_amdgcn_mfma_f32_16x16x32_bf16(a, b1, acc1, 0, 0, 0);
  }
#pragma unroll
  for (int r = 0; r < 4; ++r) {
    const int m = m0 + lc * 4 + r;
    out[(size_t)m * V_ + lr]      = acc0[r] + bias[lr];
    out[(size_t)m * V_ + 16 + lr] = acc1[r] + bias[16 + lr];
  }
}

// ---------------- launcher ----------------
extern "C" void kernel_launch(void* const* d_in, const int* in_sizes, int n_in,
                              void* d_out, int out_size, void* d_ws, size_t ws_size,
                              hipStream_t stream) {
  // sanity: dict-order inputs with expected element counts
  if (n_in != 7) return;
  const int exp_sz[7] = {B_ * T_ * F_, H_ * H_, H_ * F_, H_, H_, V_ * H_, V_};
  for (int i = 0; i < 7; ++i) if (in_sizes[i] != exp_sz[i]) return;

  const float* x    = (const float*)d_in[0];   // f32 (B,T,F)
  const int*   Wr4  = (const int*)d_in[1];     // int32 (H,H)
  const int*   Wi4  = (const int*)d_in[2];     // int32 (H,F)
  const float* Sres = (const float*)d_in[3];   // f32 (H)
  const float* Sin  = (const float*)d_in[4];   // f32 (H)
  const float* Wo   = (const float*)d_in[5];   // f32 (V,H)
  const float* Wob  = (const float*)d_in[6];   // f32 (V)
  float* out = (float*)d_out;
  char* ws = (char*)d_ws;

  // workspace layout (bytes)
  const size_t OFF_WRB = 0;                           //  8,388,608 (H*H bf16)
  const size_t OFF_WIB = 8388608;                     //    524,288 (H*F bf16)
  const size_t OFF_WOB = 8912896;                     //    131,072 (V*H bf16)
  const size_t OFF_OIN = 9043968;                     // 67,108,864 (int16 T*H*B)
  const size_t OFF_HS  = 76152832;                    // 67,108,864 (bf16 B*T*H)
  const size_t OFF_HB  = 143261696;                   //    262,144 (2 x B*H bf16 ping-pong)
  const size_t OFF_BAR = 143523840;                   //      1,024 (8 striped counters)
  const size_t NEED    = 143524864;
  if (ws_size < NEED) return;

  short* WrB = (short*)(ws + OFF_WRB);
  short* WiB = (short*)(ws + OFF_WIB);
  short* WoB = (short*)(ws + OFF_WOB);
  short* Oin = (short*)(ws + OFF_OIN);
  short* HsP = (short*)(ws + OFF_HS);
  short* Hb  = (short*)(ws + OFF_HB);
  int*   Bar = (int*)(ws + OFF_BAR);

  // h0 = 0 (ping buffer 0; buffer 1 fully written at t=0); barrier counters = 0.
  hipMemsetAsync(Hb, 0, B_ * H_ * 2, stream);
  hipMemsetAsync(Bar, 0, 1024, stream);

  pack_k<<<dim3(H_ * H_ / (4 * 256)), dim3(256), 0, stream>>>(Wr4, Wi4, Wo, WrB, WiB, WoB);
  in_gemm<<<dim3(T_, H_ / 128), dim3(256), 0, stream>>>(x, WiB, Oin);

  recur_pers<<<dim3(NBLK_), dim3(256), 0, stream>>>(WrB, Oin, Sres, Sin, Hb, HsP, Bar);

  out_gemm<<<dim3(256), dim3(256), 0, stream>>>((const unsigned short*)HsP,
                                                (const unsigned short*)WoB, Wob, out);
}

// Round 16
// 5661.358 us; speedup vs baseline: 1.3778x; 1.3778x over previous
//
#include <hip/hip_runtime.h>
#include <hip/hip_bf16.h>

typedef __attribute__((ext_vector_type(4))) int   i32x4;
typedef __attribute__((ext_vector_type(4))) float f32x4;
typedef __attribute__((ext_vector_type(4))) short s16x4;
typedef __attribute__((ext_vector_type(8))) short s16x8;

#define B_  32
#define T_  512
#define F_  128
#define H_  2048
#define V_  32
#define NBLK_ 64

static __device__ __forceinline__ int clampi16(int v) {
  v = v < -32768 ? -32768 : v;
  return v > 32767 ? 32767 : v;
}
static __device__ __forceinline__ short f2bf(float f) {
  union { __hip_bfloat16 b; short s; } u; u.b = __float2bfloat16(f); return u.s;
}
static __device__ __forceinline__ s16x8 as_s16x8(i32x4 v) {
  union { i32x4 i; s16x8 s; } u; u.i = v; return u.s;
}

// XLA-CPU tanh under legacy fast-math: Eigen/XLA rational approximation with
// FMA-contracted Horner chains. (R10-validated bit-level grading target.)
static __device__ __forceinline__ float xla_tanh_fma(float x) {
#pragma clang fp contract(off)
  const float kClamp = 7.90531110763549805f;
  float xc = fminf(fmaxf(x, -kClamp), kClamp);
  float x2 = xc * xc;
  float a;
  a = -2.76076847742355e-16f;                          // alpha_13
  a = __builtin_fmaf(a, x2, 2.00018790482477e-13f);    // alpha_11
  a = __builtin_fmaf(a, x2, -8.60467152213735e-11f);   // alpha_9
  a = __builtin_fmaf(a, x2, 5.12229709037114e-08f);    // alpha_7
  a = __builtin_fmaf(a, x2, 1.48572235717979e-05f);    // alpha_5
  a = __builtin_fmaf(a, x2, 6.37261928875436e-04f);    // alpha_3
  a = __builtin_fmaf(a, x2, 4.89352455891786e-03f);    // alpha_1
  float num = xc * a;
  float b;
  b = 1.19825839466702e-06f;                           // beta_6
  b = __builtin_fmaf(b, x2, 1.18534705686654e-04f);    // beta_4
  b = __builtin_fmaf(b, x2, 2.26843463243900e-03f);    // beta_2
  b = __builtin_fmaf(b, x2, 4.89352518554385e-03f);    // beta_0
  float r = num / b;                                   // IEEE div
  return (fabsf(x) < 0.0004f) ? x : r;
}

// ---------------- Phase 0: pack weights to bf16 (exact: |w|<=7) ----------------
__global__ __launch_bounds__(256) void pack_k(const int* __restrict__ Wr4,
                                              const int* __restrict__ Wi4,
                                              const float* __restrict__ Wo,
                                              short* __restrict__ WrB,
                                              short* __restrict__ WiB,
                                              short* __restrict__ WoB) {
  const int idx = blockIdx.x * 256 + threadIdx.x;  // grid 4096 -> 1,048,576
  {
    i32x4 v = *(const i32x4*)(Wr4 + (size_t)idx * 4);
    s16x4 o;
#pragma unroll
    for (int r = 0; r < 4; ++r) o[r] = f2bf((float)v[r]);
    *(s16x4*)(WrB + (size_t)idx * 4) = o;
  }
  if (idx < (H_ * F_ / 4)) {
    i32x4 v = *(const i32x4*)(Wi4 + (size_t)idx * 4);
    s16x4 o;
#pragma unroll
    for (int r = 0; r < 4; ++r) o[r] = f2bf((float)v[r]);
    *(s16x4*)(WiB + (size_t)idx * 4) = o;
  }
  if (idx < (V_ * H_ / 4)) {
    f32x4 f = *(const f32x4*)(Wo + (size_t)idx * 4);
    s16x4 o;
#pragma unroll
    for (int r = 0; r < 4; ++r) o[r] = f2bf(f[r]);
    *(s16x4*)(WoB + (size_t)idx * 4) = o;
  }
}

// ---------------- Phase 1: Oin[t][j][b] = clip(u_int @ Wi^T, int16) ----------------
__global__ __launch_bounds__(256) void in_gemm(const float* __restrict__ x,
                                               const short* __restrict__ WiB,
                                               short* __restrict__ Oin) {
  const int t  = blockIdx.x;
  const int jt = blockIdx.y;
  const int tid = threadIdx.x;
  const int l = tid & 63, w = tid >> 6;
  const int mh = w & 1, q = w >> 1;
  const int lr = l & 15, lc = l >> 4;
  const int brow = mh * 16 + lr;

  s16x8 af[4];
  const float* xp = x + ((size_t)brow * T_ + t) * F_;
#pragma unroll
  for (int kk = 0; kk < 4; ++kk) {
    f32x4 f0 = *(const f32x4*)(xp + kk * 32 + lc * 8);
    f32x4 f1 = *(const f32x4*)(xp + kk * 32 + lc * 8 + 4);
    s16x8 a;
#pragma unroll
    for (int c = 0; c < 4; ++c) a[c]     = f2bf(rintf(f0[c] * 7.0f));
#pragma unroll
    for (int c = 0; c < 4; ++c) a[4 + c] = f2bf(rintf(f1[c] * 7.0f));
    af[kk] = a;
  }
#pragma unroll
  for (int s = 0; s < 4; ++s) {
    const int j = jt * 128 + q * 64 + s * 16 + lr;
    f32x4 acc = {0.f, 0.f, 0.f, 0.f};
#pragma unroll
    for (int kk = 0; kk < 4; ++kk) {
      s16x8 b = *(const s16x8*)(WiB + (size_t)j * F_ + kk * 32 + lc * 8);
      acc = __builtin_amdgcn_mfma_f32_16x16x32_bf16(af[kk], b, acc, 0, 0, 0);
    }
    short* op = Oin + ((size_t)t * H_ + j) * B_ + mh * 16 + lc * 4;
    s16x4 ov;
#pragma unroll
    for (int r = 0; r < 4; ++r) ov[r] = (short)clampi16((int)acc[r]);
    *(s16x4*)op = ov;
  }
}

// ---------------- Phase 2: persistent recurrence, MALL-coherent h, fenceless ----------------
// R16: h ping-pong via inline-asm global ops with sc0 sc1 (bypass L1+L2, read/
// write at MALL). Deletes the per-step wbl2+inv whole-L2 fence ops (the R13/R14
// invariant ~15us/step). Hand-managed counted vmcnt pipeline (4x16 loads,
// double-buffered regs, sched_barrier(0) per rule #18). Barrier: vmcnt(0) drain
// -> syncthreads -> RELAXED striped atomic -> relaxed-sum poll. Numerics
// bit-identical to R10 (same MFMA chain order, same epilogue).
__global__ __launch_bounds__(256, 1) void recur_pers(const short* __restrict__ WrB,
                                                     const short* __restrict__ Oin,
                                                     const float* __restrict__ Sres,
                                                     const float* __restrict__ Sin,
                                                     short* __restrict__ Hb,
                                                     short* __restrict__ Hs,
                                                     int* __restrict__ barcnt) {
#pragma clang fp contract(off)
  const int tid = threadIdx.x;
  const int l = tid & 63, w = tid >> 6;
  const int mh = w & 1, nh = w >> 1;
  const int lr = l & 15, lc = l >> 4;
  const int jl = blockIdx.x * 32 + nh * 16 + lr;   // unit (MFMA col)
  const int b0 = mh * 16;

  const float RC49 = 1.0f / 49.0f;
  const float sres = Sres[jl] * RC49;    // fast-math: x/49 -> x*(1/49)
  const float sinl = Sin[jl]  * RC49;

  // Preload W row fragments into regs and pin (full unroll everywhere).
  const short* wrow = WrB + (size_t)jl * H_ + lc * 8;
  s16x8 wreg[64];
#pragma unroll
  for (int kk = 0; kk < 64; ++kk) {
    wreg[kk] = *(const s16x8*)(wrow + kk * 32);
    asm volatile("" : "+v"(wreg[kk]));
  }

  for (int t = 0; t < T_; ++t) {
    const short* hrow = Hb + (t & 1) * (B_ * H_) + (size_t)(b0 + lr) * H_ + lc * 8;
    short*       hout = Hb + ((t + 1) & 1) * (B_ * H_);

    const s16x4 oin = *(const s16x4*)(Oin + ((size_t)t * H_ + jl) * B_ + b0 + lc * 4);
    asm volatile("s_waitcnt vmcnt(0)" ::: "memory");   // drain: counted scheme starts at 0
    __builtin_amdgcn_sched_barrier(0);

    i32x4 a0[16], a1[16];
#pragma unroll
    for (int i = 0; i < 16; ++i)
      asm volatile("global_load_dwordx4 %0, %1, off offset:%2 sc0 sc1"
                   : "=v"(a0[i]) : "v"(hrow), "n"(i * 64) : "memory");
#pragma unroll
    for (int i = 0; i < 16; ++i)
      asm volatile("global_load_dwordx4 %0, %1, off offset:%2 sc0 sc1"
                   : "=v"(a1[i]) : "v"(hrow + 512), "n"(i * 64) : "memory");

    f32x4 acc0 = {0.f, 0.f, 0.f, 0.f}, acc1 = {0.f, 0.f, 0.f, 0.f};

    asm volatile("s_waitcnt vmcnt(16)" ::: "memory");  // batch0 landed
    __builtin_amdgcn_sched_barrier(0);
#pragma unroll
    for (int i = 0; i < 16; i += 2) {
      acc0 = __builtin_amdgcn_mfma_f32_16x16x32_bf16(as_s16x8(a0[i]),     wreg[i],     acc0, 0, 0, 0);
      acc1 = __builtin_amdgcn_mfma_f32_16x16x32_bf16(as_s16x8(a0[i + 1]), wreg[i + 1], acc1, 0, 0, 0);
    }
#pragma unroll
    for (int i = 0; i < 16; ++i)                        // batch2 -> a0
      asm volatile("global_load_dwordx4 %0, %1, off offset:%2 sc0 sc1"
                   : "=v"(a0[i]) : "v"(hrow + 1024), "n"(i * 64) : "memory");
    asm volatile("s_waitcnt vmcnt(16)" ::: "memory");  // batch1 landed
    __builtin_amdgcn_sched_barrier(0);
#pragma unroll
    for (int i = 0; i < 16; i += 2) {
      acc0 = __builtin_amdgcn_mfma_f32_16x16x32_bf16(as_s16x8(a1[i]),     wreg[16 + i],     acc0, 0, 0, 0);
      acc1 = __builtin_amdgcn_mfma_f32_16x16x32_bf16(as_s16x8(a1[i + 1]), wreg[16 + i + 1], acc1, 0, 0, 0);
    }
#pragma unroll
    for (int i = 0; i < 16; ++i)                        // batch3 -> a1
      asm volatile("global_load_dwordx4 %0, %1, off offset:%2 sc0 sc1"
                   : "=v"(a1[i]) : "v"(hrow + 1536), "n"(i * 64) : "memory");
    asm volatile("s_waitcnt vmcnt(16)" ::: "memory");  // batch2 landed
    __builtin_amdgcn_sched_barrier(0);
#pragma unroll
    for (int i = 0; i < 16; i += 2) {
      acc0 = __builtin_amdgcn_mfma_f32_16x16x32_bf16(as_s16x8(a0[i]),     wreg[32 + i],     acc0, 0, 0, 0);
      acc1 = __builtin_amdgcn_mfma_f32_16x16x32_bf16(as_s16x8(a0[i + 1]), wreg[32 + i + 1], acc1, 0, 0, 0);
    }
    asm volatile("s_waitcnt vmcnt(0)" ::: "memory");   // batch3 landed
    __builtin_amdgcn_sched_barrier(0);
#pragma unroll
    for (int i = 0; i < 16; i += 2) {
      acc0 = __builtin_amdgcn_mfma_f32_16x16x32_bf16(as_s16x8(a1[i]),     wreg[48 + i],     acc0, 0, 0, 0);
      acc1 = __builtin_amdgcn_mfma_f32_16x16x32_bf16(as_s16x8(a1[i + 1]), wreg[48 + i + 1], acc1, 0, 0, 0);
    }

#pragma unroll
    for (int r = 0; r < 4; ++r) {
      const int b = b0 + lc * 4 + r;
      const float resf = acc0[r] + acc1[r];          // exact integer in f32
      const int   res  = clampi16((int)resf);
      const float t2   = (float)oin[r] * sinl;
      const float z    = __builtin_fmaf((float)res, sres, t2);
      const float h    = xla_tanh_fma(z);
      const float hc   = fminf(fmaxf(h, -1.0f), 1.0f);
      Hs[((size_t)b * T_ + t) * H_ + jl] = f2bf(h);
      const int hq = (int)(unsigned short)f2bf(rintf(hc * 7.0f));
      asm volatile("global_store_short %0, %1, off sc0 sc1"
                   :: "v"(hout + (size_t)b * H_ + jl), "v"(hq) : "memory");
    }

    if (t != T_ - 1) {
      asm volatile("s_waitcnt vmcnt(0)" ::: "memory");  // MALL stores landed
      __syncthreads();
      if (tid == 0) {
        __hip_atomic_fetch_add(&barcnt[(blockIdx.x & 7) * 32], 1,
                               __ATOMIC_RELAXED, __HIP_MEMORY_SCOPE_AGENT);
        const int target = NBLK_ * (t + 1);
        for (;;) {
          int s = 0;
#pragma unroll
          for (int i = 0; i < 8; ++i)
            s += __hip_atomic_load(&barcnt[i * 32], __ATOMIC_RELAXED,
                                   __HIP_MEMORY_SCOPE_AGENT);
          if (s >= target) break;
          __builtin_amdgcn_s_sleep(1);
        }
      }
      __syncthreads();
    }
  }
}

// ---------------- Phase 3: out(f32) = Hs(bf16) @ Wo(bf16)^T + bias ----------------
__global__ __launch_bounds__(256) void out_gemm(const unsigned short* __restrict__ Hs,
                                                const unsigned short* __restrict__ WoB,
                                                const float* __restrict__ bias,
                                                float* __restrict__ out) {
  const int tid = threadIdx.x;
  const int l = tid & 63, w = tid >> 6;
  const int m0 = blockIdx.x * 64 + w * 16;
  const int lr = l & 15, lc = l >> 4;

  f32x4 acc0 = {0.f, 0.f, 0.f, 0.f}, acc1 = {0.f, 0.f, 0.f, 0.f};
  const unsigned short* arow = Hs  + (size_t)(m0 + lr) * H_ + lc * 8;
  const unsigned short* bp0  = WoB + (size_t)lr * H_        + lc * 8;
  const unsigned short* bp1  = WoB + (size_t)(16 + lr) * H_ + lc * 8;
#pragma unroll 8
  for (int kk = 0; kk < 64; ++kk) {
    s16x8 a  = *(const s16x8*)(arow + kk * 32);
    s16x8 b0 = *(const s16x8*)(bp0  + kk * 32);
    s16x8 b1 = *(const s16x8*)(bp1  + kk * 32);
    acc0 = __builtin_amdgcn_mfma_f32_16x16x32_bf16(a, b0, acc0, 0, 0, 0);
    acc1 = __builtin_amdgcn_mfma_f32_16x16x32_bf16(a, b1, acc1, 0, 0, 0);
  }
#pragma unroll
  for (int r = 0; r < 4; ++r) {
    const int m = m0 + lc * 4 + r;
    out[(size_t)m * V_ + lr]      = acc0[r] + bias[lr];
    out[(size_t)m * V_ + 16 + lr] = acc1[r] + bias[16 + lr];
  }
}

// ---------------- launcher ----------------
extern "C" void kernel_launch(void* const* d_in, const int* in_sizes, int n_in,
                              void* d_out, int out_size, void* d_ws, size_t ws_size,
                              hipStream_t stream) {
  // sanity: dict-order inputs with expected element counts
  if (n_in != 7) return;
  const int exp_sz[7] = {B_ * T_ * F_, H_ * H_, H_ * F_, H_, H_, V_ * H_, V_};
  for (int i = 0; i < 7; ++i) if (in_sizes[i] != exp_sz[i]) return;

  const float* x    = (const float*)d_in[0];   // f32 (B,T,F)
  const int*   Wr4  = (const int*)d_in[1];     // int32 (H,H)
  const int*   Wi4  = (const int*)d_in[2];     // int32 (H,F)
  const float* Sres = (const float*)d_in[3];   // f32 (H)
  const float* Sin  = (const float*)d_in[4];   // f32 (H)
  const float* Wo   = (const float*)d_in[5];   // f32 (V,H)
  const float* Wob  = (const float*)d_in[6];   // f32 (V)
  float* out = (float*)d_out;
  char* ws = (char*)d_ws;

  // workspace layout (bytes)
  const size_t OFF_WRB = 0;                           //  8,388,608 (H*H bf16)
  const size_t OFF_WIB = 8388608;                     //    524,288 (H*F bf16)
  const size_t OFF_WOB = 8912896;                     //    131,072 (V*H bf16)
  const size_t OFF_OIN = 9043968;                     // 67,108,864 (int16 T*H*B)
  const size_t OFF_HS  = 76152832;                    // 67,108,864 (bf16 B*T*H)
  const size_t OFF_HB  = 143261696;                   //    262,144 (2 x B*H bf16 ping-pong)
  const size_t OFF_BAR = 143523840;                   //      1,024 (8 striped counters)
  const size_t NEED    = 143524864;
  if (ws_size < NEED) return;

  short* WrB = (short*)(ws + OFF_WRB);
  short* WiB = (short*)(ws + OFF_WIB);
  short* WoB = (short*)(ws + OFF_WOB);
  short* Oin = (short*)(ws + OFF_OIN);
  short* HsP = (short*)(ws + OFF_HS);
  short* Hb  = (short*)(ws + OFF_HB);
  int*   Bar = (int*)(ws + OFF_BAR);

  // h0 = 0 (ping buffer 0; buffer 1 fully written at t=0); barrier counters = 0.
  hipMemsetAsync(Hb, 0, B_ * H_ * 2, stream);
  hipMemsetAsync(Bar, 0, 1024, stream);

  pack_k<<<dim3(H_ * H_ / (4 * 256)), dim3(256), 0, stream>>>(Wr4, Wi4, Wo, WrB, WiB, WoB);
  in_gemm<<<dim3(T_, H_ / 128), dim3(256), 0, stream>>>(x, WiB, Oin);

  recur_pers<<<dim3(NBLK_), dim3(256), 0, stream>>>(WrB, Oin, Sres, Sin, Hb, HsP, Bar);

  out_gemm<<<dim3(256), dim3(256), 0, stream>>>((const unsigned short*)HsP,
                                                (const unsigned short*)WoB, Wob, out);
}

// Round 18
// 5469.308 us; speedup vs baseline: 1.4262x; 1.0351x over previous
//
#include <hip/hip_runtime.h>
#include <hip/hip_bf16.h>

typedef __attribute__((ext_vector_type(2))) int   i32x2;
typedef __attribute__((ext_vector_type(4))) int   i32x4;
typedef __attribute__((ext_vector_type(4))) float f32x4;
typedef __attribute__((ext_vector_type(4))) short s16x4;
typedef __attribute__((ext_vector_type(8))) short s16x8;

#define B_  32
#define T_  512
#define F_  128
#define H_  2048
#define V_  32
#define NBLK_ 64

static __device__ __forceinline__ int clampi16(int v) {
  v = v < -32768 ? -32768 : v;
  return v > 32767 ? 32767 : v;
}
static __device__ __forceinline__ short f2bf(float f) {
  union { __hip_bfloat16 b; short s; } u; u.b = __float2bfloat16(f); return u.s;
}
static __device__ __forceinline__ s16x8 as_s16x8(i32x4 v) {
  union { i32x4 i; s16x8 s; } u; u.i = v; return u.s;
}
static __device__ __forceinline__ s16x4 as_s16x4(i32x2 v) {
  union { i32x2 i; s16x4 s; } u; u.i = v; return u.s;
}
static __device__ __forceinline__ i32x2 as_i32x2(s16x4 v) {
  union { s16x4 s; i32x2 i; } u; u.s = v; return u.i;
}

// XLA-CPU tanh under legacy fast-math: Eigen/XLA rational approximation with
// FMA-contracted Horner chains. (R10-validated bit-level grading target.)
static __device__ __forceinline__ float xla_tanh_fma(float x) {
#pragma clang fp contract(off)
  const float kClamp = 7.90531110763549805f;
  float xc = fminf(fmaxf(x, -kClamp), kClamp);
  float x2 = xc * xc;
  float a;
  a = -2.76076847742355e-16f;                          // alpha_13
  a = __builtin_fmaf(a, x2, 2.00018790482477e-13f);    // alpha_11
  a = __builtin_fmaf(a, x2, -8.60467152213735e-11f);   // alpha_9
  a = __builtin_fmaf(a, x2, 5.12229709037114e-08f);    // alpha_7
  a = __builtin_fmaf(a, x2, 1.48572235717979e-05f);    // alpha_5
  a = __builtin_fmaf(a, x2, 6.37261928875436e-04f);    // alpha_3
  a = __builtin_fmaf(a, x2, 4.89352455891786e-03f);    // alpha_1
  float num = xc * a;
  float b;
  b = 1.19825839466702e-06f;                           // beta_6
  b = __builtin_fmaf(b, x2, 1.18534705686654e-04f);    // beta_4
  b = __builtin_fmaf(b, x2, 2.26843463243900e-03f);    // beta_2
  b = __builtin_fmaf(b, x2, 4.89352518554385e-03f);    // beta_0
  float r = num / b;                                   // IEEE div
  return (fabsf(x) < 0.0004f) ? x : r;
}

// ---------------- Phase 0: pack weights to bf16 (exact: |w|<=7) ----------------
__global__ __launch_bounds__(256) void pack_k(const int* __restrict__ Wr4,
                                              const int* __restrict__ Wi4,
                                              const float* __restrict__ Wo,
                                              short* __restrict__ WrB,
                                              short* __restrict__ WiB,
                                              short* __restrict__ WoB) {
  const int idx = blockIdx.x * 256 + threadIdx.x;  // grid 4096 -> 1,048,576
  {
    i32x4 v = *(const i32x4*)(Wr4 + (size_t)idx * 4);
    s16x4 o;
#pragma unroll
    for (int r = 0; r < 4; ++r) o[r] = f2bf((float)v[r]);
    *(s16x4*)(WrB + (size_t)idx * 4) = o;
  }
  if (idx < (H_ * F_ / 4)) {
    i32x4 v = *(const i32x4*)(Wi4 + (size_t)idx * 4);
    s16x4 o;
#pragma unroll
    for (int r = 0; r < 4; ++r) o[r] = f2bf((float)v[r]);
    *(s16x4*)(WiB + (size_t)idx * 4) = o;
  }
  if (idx < (V_ * H_ / 4)) {
    f32x4 f = *(const f32x4*)(Wo + (size_t)idx * 4);
    s16x4 o;
#pragma unroll
    for (int r = 0; r < 4; ++r) o[r] = f2bf(f[r]);
    *(s16x4*)(WoB + (size_t)idx * 4) = o;
  }
}

// ---------------- Phase 1: Oin[t][j][b] = clip(u_int @ Wi^T, int16) ----------------
__global__ __launch_bounds__(256) void in_gemm(const float* __restrict__ x,
                                               const short* __restrict__ WiB,
                                               short* __restrict__ Oin) {
  const int t  = blockIdx.x;
  const int jt = blockIdx.y;
  const int tid = threadIdx.x;
  const int l = tid & 63, w = tid >> 6;
  const int mh = w & 1, q = w >> 1;
  const int lr = l & 15, lc = l >> 4;
  const int brow = mh * 16 + lr;

  s16x8 af[4];
  const float* xp = x + ((size_t)brow * T_ + t) * F_;
#pragma unroll
  for (int kk = 0; kk < 4; ++kk) {
    f32x4 f0 = *(const f32x4*)(xp + kk * 32 + lc * 8);
    f32x4 f1 = *(const f32x4*)(xp + kk * 32 + lc * 8 + 4);
    s16x8 a;
#pragma unroll
    for (int c = 0; c < 4; ++c) a[c]     = f2bf(rintf(f0[c] * 7.0f));
#pragma unroll
    for (int c = 0; c < 4; ++c) a[4 + c] = f2bf(rintf(f1[c] * 7.0f));
    af[kk] = a;
  }
#pragma unroll
  for (int s = 0; s < 4; ++s) {
    const int j = jt * 128 + q * 64 + s * 16 + lr;
    f32x4 acc = {0.f, 0.f, 0.f, 0.f};
#pragma unroll
    for (int kk = 0; kk < 4; ++kk) {
      s16x8 b = *(const s16x8*)(WiB + (size_t)j * F_ + kk * 32 + lc * 8);
      acc = __builtin_amdgcn_mfma_f32_16x16x32_bf16(af[kk], b, acc, 0, 0, 0);
    }
    short* op = Oin + ((size_t)t * H_ + j) * B_ + mh * 16 + lc * 4;
    s16x4 ov;
#pragma unroll
    for (int r = 0; r < 4; ++r) ov[r] = (short)clampi16((int)acc[r]);
    *(s16x4*)op = ov;
  }
}

// ---------------- Phase 2: persistent recurrence (R16 skeleton + coalesced stores) ----------------
// R18 vs R16 (working): (1) epilogue h/Hs values routed through LDS 32x36
// tiles -> 8B coalesced stores (was 2048 scattered 2B stores/block/step);
// (2) oin folded into the counted load window [oin][a0 x16][a1 x16];
// (3) exact vmcnt accounting: pre-loop drain, post-poll drain of the
// no-return arrival atomic (wave0), full vmcnt(0) before the barrier.
// Numerics bit-identical to R10.
__global__ __launch_bounds__(256, 1) void recur_pers(const short* __restrict__ WrB,
                                                     const short* __restrict__ Oin,
                                                     const float* __restrict__ Sres,
                                                     const float* __restrict__ Sin,
                                                     short* __restrict__ Hb,
                                                     short* __restrict__ Hs,
                                                     int* __restrict__ barcnt) {
#pragma clang fp contract(off)
  __shared__ short hqt[32][36];
  __shared__ short hst[32][36];

  const int tid = threadIdx.x;
  const int l = tid & 63, w = tid >> 6;
  const int mh = w & 1, nh = w >> 1;
  const int lr = l & 15, lc = l >> 4;
  const int jloc = nh * 16 + lr;
  const int jl = blockIdx.x * 32 + jloc;           // unit (MFMA col)
  const int b0 = mh * 16;
  const int jblk = blockIdx.x * 32;

  const float RC49 = 1.0f / 49.0f;
  const float sres = Sres[jl] * RC49;    // fast-math: x/49 -> x*(1/49)
  const float sinl = Sin[jl]  * RC49;

  // Preload W row fragments into regs and pin.
  const short* wrow = WrB + (size_t)jl * H_ + lc * 8;
  s16x8 wreg[64];
#pragma unroll
  for (int kk = 0; kk < 64; ++kk) {
    wreg[kk] = *(const s16x8*)(wrow + kk * 32);
    asm volatile("" : "+v"(wreg[kk]));
  }

  // store-phase mapping: thread tid -> (bs, cs)
  const int bs = tid >> 3;          // 0..31
  const int cs = tid & 7;           // 0..7  (4-short chunk)

  asm volatile("s_waitcnt vmcnt(0)" ::: "memory");  // counted scheme starts at 0
  __builtin_amdgcn_sched_barrier(0);

  for (int t = 0; t < T_; ++t) {
    const short* hrow = Hb + (t & 1) * (B_ * H_) + (size_t)(b0 + lr) * H_ + lc * 8;
    short*       hout = Hb + ((t + 1) & 1) * (B_ * H_);

    // counted window: [oin][a0 x16][a1 x16]
    i32x2 oinr;
    {
      const short* op = Oin + ((size_t)t * H_ + jl) * B_ + b0 + lc * 4;
      asm volatile("global_load_dwordx2 %0, %1, off"
                   : "=v"(oinr) : "v"(op) : "memory");
    }
    i32x4 a0[16], a1[16];
#pragma unroll
    for (int i = 0; i < 16; ++i)
      asm volatile("global_load_dwordx4 %0, %1, off offset:%2 sc0 sc1"
                   : "=v"(a0[i]) : "v"(hrow), "n"(i * 64) : "memory");
#pragma unroll
    for (int i = 0; i < 16; ++i)
      asm volatile("global_load_dwordx4 %0, %1, off offset:%2 sc0 sc1"
                   : "=v"(a1[i]) : "v"(hrow + 512), "n"(i * 64) : "memory");

    f32x4 acc0 = {0.f, 0.f, 0.f, 0.f}, acc1 = {0.f, 0.f, 0.f, 0.f};

    asm volatile("s_waitcnt vmcnt(16)" ::: "memory");  // oin + batch0 landed
    __builtin_amdgcn_sched_barrier(0);
#pragma unroll
    for (int i = 0; i < 16; i += 2) {
      acc0 = __builtin_amdgcn_mfma_f32_16x16x32_bf16(as_s16x8(a0[i]),     wreg[i],     acc0, 0, 0, 0);
      acc1 = __builtin_amdgcn_mfma_f32_16x16x32_bf16(as_s16x8(a0[i + 1]), wreg[i + 1], acc1, 0, 0, 0);
    }
#pragma unroll
    for (int i = 0; i < 16; ++i)                        // batch2 -> a0
      asm volatile("global_load_dwordx4 %0, %1, off offset:%2 sc0 sc1"
                   : "=v"(a0[i]) : "v"(hrow + 1024), "n"(i * 64) : "memory");
    asm volatile("s_waitcnt vmcnt(16)" ::: "memory");  // batch1 landed
    __builtin_amdgcn_sched_barrier(0);
#pragma unroll
    for (int i = 0; i < 16; i += 2) {
      acc0 = __builtin_amdgcn_mfma_f32_16x16x32_bf16(as_s16x8(a1[i]),     wreg[16 + i],     acc0, 0, 0, 0);
      acc1 = __builtin_amdgcn_mfma_f32_16x16x32_bf16(as_s16x8(a1[i + 1]), wreg[16 + i + 1], acc1, 0, 0, 0);
    }
#pragma unroll
    for (int i = 0; i < 16; ++i)                        // batch3 -> a1
      asm volatile("global_load_dwordx4 %0, %1, off offset:%2 sc0 sc1"
                   : "=v"(a1[i]) : "v"(hrow + 1536), "n"(i * 64) : "memory");
    asm volatile("s_waitcnt vmcnt(16)" ::: "memory");  // batch2 landed
    __builtin_amdgcn_sched_barrier(0);
#pragma unroll
    for (int i = 0; i < 16; i += 2) {
      acc0 = __builtin_amdgcn_mfma_f32_16x16x32_bf16(as_s16x8(a0[i]),     wreg[32 + i],     acc0, 0, 0, 0);
      acc1 = __builtin_amdgcn_mfma_f32_16x16x32_bf16(as_s16x8(a0[i + 1]), wreg[32 + i + 1], acc1, 0, 0, 0);
    }
    asm volatile("s_waitcnt vmcnt(0)" ::: "memory");   // batch3 landed
    __builtin_amdgcn_sched_barrier(0);
#pragma unroll
    for (int i = 0; i < 16; i += 2) {
      acc0 = __builtin_amdgcn_mfma_f32_16x16x32_bf16(as_s16x8(a1[i]),     wreg[48 + i],     acc0, 0, 0, 0);
      acc1 = __builtin_amdgcn_mfma_f32_16x16x32_bf16(as_s16x8(a1[i + 1]), wreg[48 + i + 1], acc1, 0, 0, 0);
    }

    const s16x4 oin = as_s16x4(oinr);
#pragma unroll
    for (int r = 0; r < 4; ++r) {
      const int b = b0 + lc * 4 + r;
      const float resf = acc0[r] + acc1[r];          // exact integer in f32
      const int   res  = clampi16((int)resf);
      const float t2   = (float)oin[r] * sinl;
      const float z    = __builtin_fmaf((float)res, sres, t2);
      const float h    = xla_tanh_fma(z);
      const float hc   = fminf(fmaxf(h, -1.0f), 1.0f);
      hqt[b][jloc] = f2bf(rintf(hc * 7.0f));
      hst[b][jloc] = f2bf(h);
    }

    __syncthreads();   // LDS tiles complete

    // coalesced stores: 8B per thread for h (MALL) and Hs (cached)
    {
      const i32x2 hqv = as_i32x2(*(const s16x4*)&hqt[bs][cs * 4]);
      const i32x2 hsv = as_i32x2(*(const s16x4*)&hst[bs][cs * 4]);
      short* hq_dst = hout + (size_t)bs * H_ + jblk + cs * 4;
      short* hs_dst = Hs + ((size_t)bs * T_ + t) * H_ + jblk + cs * 4;
      asm volatile("global_store_dwordx2 %0, %1, off sc0 sc1"
                   :: "v"(hq_dst), "v"(hqv) : "memory");
      asm volatile("global_store_dwordx2 %0, %1, off"
                   :: "v"(hs_dst), "v"(hsv) : "memory");
    }

    if (t != T_ - 1) {
      asm volatile("s_waitcnt vmcnt(0)" ::: "memory");  // both stores landed
      __syncthreads();                                   // whole block drained
      if (tid == 0) {
        __hip_atomic_fetch_add(&barcnt[(blockIdx.x & 7) * 32], 1,
                               __ATOMIC_RELAXED, __HIP_MEMORY_SCOPE_AGENT);
        const int target = NBLK_ * (t + 1);
        for (;;) {
          int s = 0;
#pragma unroll
          for (int i = 0; i < 8; ++i)
            s += __hip_atomic_load(&barcnt[i * 32], __ATOMIC_RELAXED,
                                   __HIP_MEMORY_SCOPE_AGENT);
          if (s >= target) break;
          __builtin_amdgcn_s_sleep(1);
        }
        asm volatile("s_waitcnt vmcnt(0)" ::: "memory"); // drain arrival atomic
      }
      __syncthreads();
    }
  }
}

// ---------------- Phase 3: out(f32) = Hs(bf16) @ Wo(bf16)^T + bias ----------------
__global__ __launch_bounds__(256) void out_gemm(const unsigned short* __restrict__ Hs,
                                                const unsigned short* __restrict__ WoB,
                                                const float* __restrict__ bias,
                                                float* __restrict__ out) {
  const int tid = threadIdx.x;
  const int l = tid & 63, w = tid >> 6;
  const int m0 = blockIdx.x * 64 + w * 16;
  const int lr = l & 15, lc = l >> 4;

  f32x4 acc0 = {0.f, 0.f, 0.f, 0.f}, acc1 = {0.f, 0.f, 0.f, 0.f};
  const unsigned short* arow = Hs  + (size_t)(m0 + lr) * H_ + lc * 8;
  const unsigned short* bp0  = WoB + (size_t)lr * H_        + lc * 8;
  const unsigned short* bp1  = WoB + (size_t)(16 + lr) * H_ + lc * 8;
#pragma unroll 8
  for (int kk = 0; kk < 64; ++kk) {
    s16x8 a  = *(const s16x8*)(arow + kk * 32);
    s16x8 b0 = *(const s16x8*)(bp0  + kk * 32);
    s16x8 b1 = *(const s16x8*)(bp1  + kk * 32);
    acc0 = __builtin_amdgcn_mfma_f32_16x16x32_bf16(a, b0, acc0, 0, 0, 0);
    acc1 = __builtin_amdgcn_mfma_f32_16x16x32_bf16(a, b1, acc1, 0, 0, 0);
  }
#pragma unroll
  for (int r = 0; r < 4; ++r) {
    const int m = m0 + lc * 4 + r;
    out[(size_t)m * V_ + lr]      = acc0[r] + bias[lr];
    out[(size_t)m * V_ + 16 + lr] = acc1[r] + bias[16 + lr];
  }
}

// ---------------- launcher ----------------
extern "C" void kernel_launch(void* const* d_in, const int* in_sizes, int n_in,
                              void* d_out, int out_size, void* d_ws, size_t ws_size,
                              hipStream_t stream) {
  // sanity: dict-order inputs with expected element counts
  if (n_in != 7) return;
  const int exp_sz[7] = {B_ * T_ * F_, H_ * H_, H_ * F_, H_, H_, V_ * H_, V_};
  for (int i = 0; i < 7; ++i) if (in_sizes[i] != exp_sz[i]) return;

  const float* x    = (const float*)d_in[0];   // f32 (B,T,F)
  const int*   Wr4  = (const int*)d_in[1];     // int32 (H,H)
  const int*   Wi4  = (const int*)d_in[2];     // int32 (H,F)
  const float* Sres = (const float*)d_in[3];   // f32 (H)
  const float* Sin  = (const float*)d_in[4];   // f32 (H)
  const float* Wo   = (const float*)d_in[5];   // f32 (V,H)
  const float* Wob  = (const float*)d_in[6];   // f32 (V)
  float* out = (float*)d_out;
  char* ws = (char*)d_ws;

  // workspace layout (bytes)
  const size_t OFF_WRB = 0;                           //  8,388,608 (H*H bf16)
  const size_t OFF_WIB = 8388608;                     //    524,288 (H*F bf16)
  const size_t OFF_WOB = 8912896;                     //    131,072 (V*H bf16)
  const size_t OFF_OIN = 9043968;                     // 67,108,864 (int16 T*H*B)
  const size_t OFF_HS  = 76152832;                    // 67,108,864 (bf16 B*T*H)
  const size_t OFF_HB  = 143261696;                   //    262,144 (2 x B*H bf16 ping-pong)
  const size_t OFF_BAR = 143523840;                   //      1,024 (8 striped counters)
  const size_t NEED    = 143524864;
  if (ws_size < NEED) return;

  short* WrB = (short*)(ws + OFF_WRB);
  short* WiB = (short*)(ws + OFF_WIB);
  short* WoB = (short*)(ws + OFF_WOB);
  short* Oin = (short*)(ws + OFF_OIN);
  short* HsP = (short*)(ws + OFF_HS);
  short* Hb  = (short*)(ws + OFF_HB);
  int*   Bar = (int*)(ws + OFF_BAR);

  // h0 = 0 (ping buffer 0; buffer 1 fully written at t=0); barrier counters = 0.
  hipMemsetAsync(Hb, 0, B_ * H_ * 2, stream);
  hipMemsetAsync(Bar, 0, 1024, stream);

  pack_k<<<dim3(H_ * H_ / (4 * 256)), dim3(256), 0, stream>>>(Wr4, Wi4, Wo, WrB, WiB, WoB);
  in_gemm<<<dim3(T_, H_ / 128), dim3(256), 0, stream>>>(x, WiB, Oin);

  recur_pers<<<dim3(NBLK_), dim3(256), 0, stream>>>(WrB, Oin, Sres, Sin, Hb, HsP, Bar);

  out_gemm<<<dim3(256), dim3(256), 0, stream>>>((const unsigned short*)HsP,
                                                (const unsigned short*)WoB, Wob, out);
}

// Round 19
// 4392.948 us; speedup vs baseline: 1.7757x; 1.2450x over previous
//
#include <hip/hip_runtime.h>
#include <hip/hip_bf16.h>

typedef __attribute__((ext_vector_type(2))) int   i32x2;
typedef __attribute__((ext_vector_type(4))) int   i32x4;
typedef __attribute__((ext_vector_type(4))) float f32x4;
typedef __attribute__((ext_vector_type(4))) short s16x4;
typedef __attribute__((ext_vector_type(8))) short s16x8;

#define B_  32
#define T_  512
#define F_  128
#define H_  2048
#define V_  32
#define NBLK_ 64

static __device__ __forceinline__ int clampi16(int v) {
  v = v < -32768 ? -32768 : v;
  return v > 32767 ? 32767 : v;
}
static __device__ __forceinline__ short f2bf(float f) {
  union { __hip_bfloat16 b; short s; } u; u.b = __float2bfloat16(f); return u.s;
}
static __device__ __forceinline__ s16x8 as_s16x8(i32x4 v) {
  union { i32x4 i; s16x8 s; } u; u.i = v; return u.s;
}
static __device__ __forceinline__ s16x4 as_s16x4(i32x2 v) {
  union { i32x2 i; s16x4 s; } u; u.i = v; return u.s;
}
static __device__ __forceinline__ i32x2 as_i32x2(s16x4 v) {
  union { s16x4 s; i32x2 i; } u; u.s = v; return u.i;
}

// XLA-CPU tanh under legacy fast-math: Eigen/XLA rational approximation with
// FMA-contracted Horner chains. (R10-validated bit-level grading target.)
static __device__ __forceinline__ float xla_tanh_fma(float x) {
#pragma clang fp contract(off)
  const float kClamp = 7.90531110763549805f;
  float xc = fminf(fmaxf(x, -kClamp), kClamp);
  float x2 = xc * xc;
  float a;
  a = -2.76076847742355e-16f;                          // alpha_13
  a = __builtin_fmaf(a, x2, 2.00018790482477e-13f);    // alpha_11
  a = __builtin_fmaf(a, x2, -8.60467152213735e-11f);   // alpha_9
  a = __builtin_fmaf(a, x2, 5.12229709037114e-08f);    // alpha_7
  a = __builtin_fmaf(a, x2, 1.48572235717979e-05f);    // alpha_5
  a = __builtin_fmaf(a, x2, 6.37261928875436e-04f);    // alpha_3
  a = __builtin_fmaf(a, x2, 4.89352455891786e-03f);    // alpha_1
  float num = xc * a;
  float b;
  b = 1.19825839466702e-06f;                           // beta_6
  b = __builtin_fmaf(b, x2, 1.18534705686654e-04f);    // beta_4
  b = __builtin_fmaf(b, x2, 2.26843463243900e-03f);    // beta_2
  b = __builtin_fmaf(b, x2, 4.89352518554385e-03f);    // beta_0
  float r = num / b;                                   // IEEE div
  return (fabsf(x) < 0.0004f) ? x : r;
}

// ---------------- Phase 0: pack weights to bf16 (exact: |w|<=7) ----------------
__global__ __launch_bounds__(256) void pack_k(const int* __restrict__ Wr4,
                                              const int* __restrict__ Wi4,
                                              const float* __restrict__ Wo,
                                              short* __restrict__ WrB,
                                              short* __restrict__ WiB,
                                              short* __restrict__ WoB) {
  const int idx = blockIdx.x * 256 + threadIdx.x;  // grid 4096 -> 1,048,576
  {
    i32x4 v = *(const i32x4*)(Wr4 + (size_t)idx * 4);
    s16x4 o;
#pragma unroll
    for (int r = 0; r < 4; ++r) o[r] = f2bf((float)v[r]);
    *(s16x4*)(WrB + (size_t)idx * 4) = o;
  }
  if (idx < (H_ * F_ / 4)) {
    i32x4 v = *(const i32x4*)(Wi4 + (size_t)idx * 4);
    s16x4 o;
#pragma unroll
    for (int r = 0; r < 4; ++r) o[r] = f2bf((float)v[r]);
    *(s16x4*)(WiB + (size_t)idx * 4) = o;
  }
  if (idx < (V_ * H_ / 4)) {
    f32x4 f = *(const f32x4*)(Wo + (size_t)idx * 4);
    s16x4 o;
#pragma unroll
    for (int r = 0; r < 4; ++r) o[r] = f2bf(f[r]);
    *(s16x4*)(WoB + (size_t)idx * 4) = o;
  }
}

// ---------------- Phase 1: Oin[t][j][b] = clip(u_int @ Wi^T, int16) ----------------
__global__ __launch_bounds__(256) void in_gemm(const float* __restrict__ x,
                                               const short* __restrict__ WiB,
                                               short* __restrict__ Oin) {
  const int t  = blockIdx.x;
  const int jt = blockIdx.y;
  const int tid = threadIdx.x;
  const int l = tid & 63, w = tid >> 6;
  const int mh = w & 1, q = w >> 1;
  const int lr = l & 15, lc = l >> 4;
  const int brow = mh * 16 + lr;

  s16x8 af[4];
  const float* xp = x + ((size_t)brow * T_ + t) * F_;
#pragma unroll
  for (int kk = 0; kk < 4; ++kk) {
    f32x4 f0 = *(const f32x4*)(xp + kk * 32 + lc * 8);
    f32x4 f1 = *(const f32x4*)(xp + kk * 32 + lc * 8 + 4);
    s16x8 a;
#pragma unroll
    for (int c = 0; c < 4; ++c) a[c]     = f2bf(rintf(f0[c] * 7.0f));
#pragma unroll
    for (int c = 0; c < 4; ++c) a[4 + c] = f2bf(rintf(f1[c] * 7.0f));
    af[kk] = a;
  }
#pragma unroll
  for (int s = 0; s < 4; ++s) {
    const int j = jt * 128 + q * 64 + s * 16 + lr;
    f32x4 acc = {0.f, 0.f, 0.f, 0.f};
#pragma unroll
    for (int kk = 0; kk < 4; ++kk) {
      s16x8 b = *(const s16x8*)(WiB + (size_t)j * F_ + kk * 32 + lc * 8);
      acc = __builtin_amdgcn_mfma_f32_16x16x32_bf16(af[kk], b, acc, 0, 0, 0);
    }
    short* op = Oin + ((size_t)t * H_ + j) * B_ + mh * 16 + lc * 4;
    s16x4 ov;
#pragma unroll
    for (int r = 0; r < 4; ++r) ov[r] = (short)clampi16((int)acc[r]);
    *(s16x4*)op = ov;
  }
}

// ---------------- Phase 2: persistent recurrence (K-split, dedup'd loads) ----------------
// R19 vs R18: waves (mh,0)/(mh,1) loaded IDENTICAL A-fragments (nh absent
// from the A address). Now wave (mh,nh) loads only K-half nh (32 frags, one
// issue window -> ONE MALL round trip) and computes partials for BOTH unit
// halves (A reused x2, still 64 MFMA/wave). Partials exchanged via LDS and
// summed -- exact integers, any association bit-identical. Fabric read
// traffic halves (16 -> 8 MB/step). Stores/barrier = proven R18 protocol.
__global__ __launch_bounds__(256, 1) void recur_pers(const short* __restrict__ WrB,
                                                     const short* __restrict__ Oin,
                                                     const float* __restrict__ Sres,
                                                     const float* __restrict__ Sin,
                                                     short* __restrict__ Hb,
                                                     short* __restrict__ Hs,
                                                     int* __restrict__ barcnt) {
#pragma clang fp contract(off)
  __shared__ short hqt[32][36];
  __shared__ short hst[32][36];
  __shared__ f32x4 xch[2][2][64];   // [mh][uh][lane]

  const int tid = threadIdx.x;
  const int l = tid & 63, w = tid >> 6;
  const int mh = w & 1, nh = w >> 1;
  const int lr = l & 15, lc = l >> 4;
  const int jloc = nh * 16 + lr;
  const int jl = blockIdx.x * 32 + jloc;           // unit this wave FINALIZES
  const int b0 = mh * 16;
  const int jblk = blockIdx.x * 32;

  const float RC49 = 1.0f / 49.0f;
  const float sres = Sres[jl] * RC49;    // fast-math: x/49 -> x*(1/49)
  const float sinl = Sin[jl]  * RC49;

  // W fragments for BOTH unit halves, K-half nh only. 64 x s16x8, pinned.
  const short* wrow0 = WrB + (size_t)(jblk + lr) * H_      + nh * 1024 + lc * 8;
  const short* wrow1 = WrB + (size_t)(jblk + 16 + lr) * H_ + nh * 1024 + lc * 8;
  s16x8 wreg0[32], wreg1[32];
#pragma unroll
  for (int kk = 0; kk < 32; ++kk) {
    wreg0[kk] = *(const s16x8*)(wrow0 + kk * 32);
    asm volatile("" : "+v"(wreg0[kk]));
    wreg1[kk] = *(const s16x8*)(wrow1 + kk * 32);
    asm volatile("" : "+v"(wreg1[kk]));
  }

  // store-phase mapping: thread tid -> (bs, cs)
  const int bs = tid >> 3;          // 0..31
  const int cs = tid & 7;           // 0..7  (4-short chunk)

  asm volatile("s_waitcnt vmcnt(0)" ::: "memory");  // counted scheme starts at 0
  __builtin_amdgcn_sched_barrier(0);

  for (int t = 0; t < T_; ++t) {
    const short* hrow = Hb + (t & 1) * (B_ * H_)
                      + (size_t)(b0 + lr) * H_ + nh * 1024 + lc * 8;
    short* hout = Hb + ((t + 1) & 1) * (B_ * H_);

    // counted window: [oin][a x32] -- all issued up front, one round trip
    i32x2 oinr;
    {
      const short* op = Oin + ((size_t)t * H_ + jl) * B_ + b0 + lc * 4;
      asm volatile("global_load_dwordx2 %0, %1, off"
                   : "=v"(oinr) : "v"(op) : "memory");
    }
    i32x4 a[32];
#pragma unroll
    for (int i = 0; i < 32; ++i)
      asm volatile("global_load_dwordx4 %0, %1, off offset:%2 sc0 sc1"
                   : "=v"(a[i]) : "v"(hrow), "n"(i * 64) : "memory");

    f32x4 accE0 = {0.f, 0.f, 0.f, 0.f}, accO0 = {0.f, 0.f, 0.f, 0.f};
    f32x4 accE1 = {0.f, 0.f, 0.f, 0.f}, accO1 = {0.f, 0.f, 0.f, 0.f};

    asm volatile("s_waitcnt vmcnt(16)" ::: "memory");  // oin + first 16 landed
    __builtin_amdgcn_sched_barrier(0);
#pragma unroll
    for (int i = 0; i < 16; i += 2) {
      accE0 = __builtin_amdgcn_mfma_f32_16x16x32_bf16(as_s16x8(a[i]),     wreg0[i],     accE0, 0, 0, 0);
      accE1 = __builtin_amdgcn_mfma_f32_16x16x32_bf16(as_s16x8(a[i]),     wreg1[i],     accE1, 0, 0, 0);
      accO0 = __builtin_amdgcn_mfma_f32_16x16x32_bf16(as_s16x8(a[i + 1]), wreg0[i + 1], accO0, 0, 0, 0);
      accO1 = __builtin_amdgcn_mfma_f32_16x16x32_bf16(as_s16x8(a[i + 1]), wreg1[i + 1], accO1, 0, 0, 0);
    }
    asm volatile("s_waitcnt vmcnt(0)" ::: "memory");   // rest landed
    __builtin_amdgcn_sched_barrier(0);
#pragma unroll
    for (int i = 16; i < 32; i += 2) {
      accE0 = __builtin_amdgcn_mfma_f32_16x16x32_bf16(as_s16x8(a[i]),     wreg0[i],     accE0, 0, 0, 0);
      accE1 = __builtin_amdgcn_mfma_f32_16x16x32_bf16(as_s16x8(a[i]),     wreg1[i],     accE1, 0, 0, 0);
      accO0 = __builtin_amdgcn_mfma_f32_16x16x32_bf16(as_s16x8(a[i + 1]), wreg0[i + 1], accO0, 0, 0, 0);
      accO1 = __builtin_amdgcn_mfma_f32_16x16x32_bf16(as_s16x8(a[i + 1]), wreg1[i + 1], accO1, 0, 0, 0);
    }

    // merge even/odd chains (exact ints), exchange the half we don't finalize
    f32x4 own0, own1;
#pragma unroll
    for (int r = 0; r < 4; ++r) { own0[r] = accE0[r] + accO0[r]; own1[r] = accE1[r] + accO1[r]; }
    xch[mh][1 - nh][l] = (nh == 0) ? own1 : own0;
    __syncthreads();
    const f32x4 part = xch[mh][nh][l];
    const f32x4 mine = (nh == 0) ? own0 : own1;

    const s16x4 oin = as_s16x4(oinr);
#pragma unroll
    for (int r = 0; r < 4; ++r) {
      const int b = b0 + lc * 4 + r;
      const float resf = mine[r] + part[r];          // exact integer in f32
      const int   res  = clampi16((int)resf);
      const float t2   = (float)oin[r] * sinl;
      const float z    = __builtin_fmaf((float)res, sres, t2);
      const float h    = xla_tanh_fma(z);
      const float hc   = fminf(fmaxf(h, -1.0f), 1.0f);
      hqt[b][jloc] = f2bf(rintf(hc * 7.0f));
      hst[b][jloc] = f2bf(h);
    }

    __syncthreads();   // LDS tiles complete

    // coalesced stores: 8B per thread for h (MALL) and Hs (cached)
    {
      const i32x2 hqv = as_i32x2(*(const s16x4*)&hqt[bs][cs * 4]);
      const i32x2 hsv = as_i32x2(*(const s16x4*)&hst[bs][cs * 4]);
      short* hq_dst = hout + (size_t)bs * H_ + jblk + cs * 4;
      short* hs_dst = Hs + ((size_t)bs * T_ + t) * H_ + jblk + cs * 4;
      asm volatile("global_store_dwordx2 %0, %1, off sc0 sc1"
                   :: "v"(hq_dst), "v"(hqv) : "memory");
      asm volatile("global_store_dwordx2 %0, %1, off"
                   :: "v"(hs_dst), "v"(hsv) : "memory");
    }

    if (t != T_ - 1) {
      asm volatile("s_waitcnt vmcnt(0)" ::: "memory");  // both stores landed
      __syncthreads();                                   // whole block drained
      if (tid == 0) {
        __hip_atomic_fetch_add(&barcnt[(blockIdx.x & 7) * 32], 1,
                               __ATOMIC_RELAXED, __HIP_MEMORY_SCOPE_AGENT);
        const int target = NBLK_ * (t + 1);
        for (;;) {
          int s = 0;
#pragma unroll
          for (int i = 0; i < 8; ++i)
            s += __hip_atomic_load(&barcnt[i * 32], __ATOMIC_RELAXED,
                                   __HIP_MEMORY_SCOPE_AGENT);
          if (s >= target) break;
          __builtin_amdgcn_s_sleep(1);
        }
        asm volatile("s_waitcnt vmcnt(0)" ::: "memory"); // drain arrival atomic
      }
      __syncthreads();
    }
  }
}

// ---------------- Diagnostic: bare barrier cost, 128 iterations ----------------
// Separate counters; no effect on outputs. rocprof dur/128 = barrier floor.
__global__ __launch_bounds__(256, 1) void diag_bar(int* __restrict__ bar2) {
  const int tid = threadIdx.x;
  for (int t = 0; t < 128; ++t) {
    __syncthreads();
    if (tid == 0) {
      __hip_atomic_fetch_add(&bar2[(blockIdx.x & 7) * 32], 1,
                             __ATOMIC_RELAXED, __HIP_MEMORY_SCOPE_AGENT);
      const int target = NBLK_ * (t + 1);
      for (;;) {
        int s = 0;
#pragma unroll
        for (int i = 0; i < 8; ++i)
          s += __hip_atomic_load(&bar2[i * 32], __ATOMIC_RELAXED,
                                 __HIP_MEMORY_SCOPE_AGENT);
        if (s >= target) break;
        __builtin_amdgcn_s_sleep(1);
      }
      asm volatile("s_waitcnt vmcnt(0)" ::: "memory");
    }
    __syncthreads();
  }
}

// ---------------- Phase 3: out(f32) = Hs(bf16) @ Wo(bf16)^T + bias ----------------
__global__ __launch_bounds__(256) void out_gemm(const unsigned short* __restrict__ Hs,
                                                const unsigned short* __restrict__ WoB,
                                                const float* __restrict__ bias,
                                                float* __restrict__ out) {
  const int tid = threadIdx.x;
  const int l = tid & 63, w = tid >> 6;
  const int m0 = blockIdx.x * 64 + w * 16;
  const int lr = l & 15, lc = l >> 4;

  f32x4 acc0 = {0.f, 0.f, 0.f, 0.f}, acc1 = {0.f, 0.f, 0.f, 0.f};
  const unsigned short* arow = Hs  + (size_t)(m0 + lr) * H_ + lc * 8;
  const unsigned short* bp0  = WoB + (size_t)lr * H_        + lc * 8;
  const unsigned short* bp1  = WoB + (size_t)(16 + lr) * H_ + lc * 8;
#pragma unroll 8
  for (int kk = 0; kk < 64; ++kk) {
    s16x8 a  = *(const s16x8*)(arow + kk * 32);
    s16x8 b0 = *(const s16x8*)(bp0  + kk * 32);
    s16x8 b1 = *(const s16x8*)(bp1  + kk * 32);
    acc0 = __builtin_amdgcn_mfma_f32_16x16x32_bf16(a, b0, acc0, 0, 0, 0);
    acc1 = __builtin_amdgcn_mfma_f32_16x16x32_bf16(a, b1, acc1, 0, 0, 0);
  }
#pragma unroll
  for (int r = 0; r < 4; ++r) {
    const int m = m0 + lc * 4 + r;
    out[(size_t)m * V_ + lr]      = acc0[r] + bias[lr];
    out[(size_t)m * V_ + 16 + lr] = acc1[r] + bias[16 + lr];
  }
}

// ---------------- launcher ----------------
extern "C" void kernel_launch(void* const* d_in, const int* in_sizes, int n_in,
                              void* d_out, int out_size, void* d_ws, size_t ws_size,
                              hipStream_t stream) {
  // sanity: dict-order inputs with expected element counts
  if (n_in != 7) return;
  const int exp_sz[7] = {B_ * T_ * F_, H_ * H_, H_ * F_, H_, H_, V_ * H_, V_};
  for (int i = 0; i < 7; ++i) if (in_sizes[i] != exp_sz[i]) return;

  const float* x    = (const float*)d_in[0];   // f32 (B,T,F)
  const int*   Wr4  = (const int*)d_in[1];     // int32 (H,H)
  const int*   Wi4  = (const int*)d_in[2];     // int32 (H,F)
  const float* Sres = (const float*)d_in[3];   // f32 (H)
  const float* Sin  = (const float*)d_in[4];   // f32 (H)
  const float* Wo   = (const float*)d_in[5];   // f32 (V,H)
  const float* Wob  = (const float*)d_in[6];   // f32 (V)
  float* out = (float*)d_out;
  char* ws = (char*)d_ws;

  // workspace layout (bytes)
  const size_t OFF_WRB = 0;                           //  8,388,608 (H*H bf16)
  const size_t OFF_WIB = 8388608;                     //    524,288 (H*F bf16)
  const size_t OFF_WOB = 8912896;                     //    131,072 (V*H bf16)
  const size_t OFF_OIN = 9043968;                     // 67,108,864 (int16 T*H*B)
  const size_t OFF_HS  = 76152832;                    // 67,108,864 (bf16 B*T*H)
  const size_t OFF_HB  = 143261696;                   //    262,144 (2 x B*H bf16 ping-pong)
  const size_t OFF_BAR = 143523840;                   //      1,024 (8 striped counters)
  const size_t OFF_BR2 = 143524864;                   //      1,024 (diag counters)
  const size_t NEED    = 143525888;
  if (ws_size < NEED) return;

  short* WrB = (short*)(ws + OFF_WRB);
  short* WiB = (short*)(ws + OFF_WIB);
  short* WoB = (short*)(ws + OFF_WOB);
  short* Oin = (short*)(ws + OFF_OIN);
  short* HsP = (short*)(ws + OFF_HS);
  short* Hb  = (short*)(ws + OFF_HB);
  int*   Bar = (int*)(ws + OFF_BAR);
  int*   Br2 = (int*)(ws + OFF_BR2);

  // h0 = 0 (ping buffer 0; buffer 1 fully written at t=0); counters = 0.
  hipMemsetAsync(Hb, 0, B_ * H_ * 2, stream);
  hipMemsetAsync(Bar, 0, 2048, stream);

  pack_k<<<dim3(H_ * H_ / (4 * 256)), dim3(256), 0, stream>>>(Wr4, Wi4, Wo, WrB, WiB, WoB);
  in_gemm<<<dim3(T_, H_ / 128), dim3(256), 0, stream>>>(x, WiB, Oin);

  recur_pers<<<dim3(NBLK_), dim3(256), 0, stream>>>(WrB, Oin, Sres, Sin, Hb, HsP, Bar);

  out_gemm<<<dim3(256), dim3(256), 0, stream>>>((const unsigned short*)HsP,
                                                (const unsigned short*)WoB, Wob, out);

  diag_bar<<<dim3(NBLK_), dim3(256), 0, stream>>>(Br2);
}

// Round 20
// 3571.602 us; speedup vs baseline: 2.1840x; 1.2300x over previous
//
#include <hip/hip_runtime.h>
#include <hip/hip_bf16.h>

typedef __attribute__((ext_vector_type(2))) int   i32x2;
typedef __attribute__((ext_vector_type(4))) int   i32x4;
typedef __attribute__((ext_vector_type(4))) float f32x4;
typedef __attribute__((ext_vector_type(4))) short s16x4;
typedef __attribute__((ext_vector_type(8))) short s16x8;

#define B_  32
#define T_  512
#define F_  128
#define H_  2048
#define V_  32
#define NBLK_ 64

static __device__ __forceinline__ int clampi16(int v) {
  v = v < -32768 ? -32768 : v;
  return v > 32767 ? 32767 : v;
}
static __device__ __forceinline__ short f2bf(float f) {
  union { __hip_bfloat16 b; short s; } u; u.b = __float2bfloat16(f); return u.s;
}
static __device__ __forceinline__ s16x8 as_s16x8(i32x4 v) {
  union { i32x4 i; s16x8 s; } u; u.i = v; return u.s;
}
static __device__ __forceinline__ s16x4 as_s16x4(i32x2 v) {
  union { i32x2 i; s16x4 s; } u; u.i = v; return u.s;
}
static __device__ __forceinline__ i32x2 as_i32x2(s16x4 v) {
  union { s16x4 s; i32x2 i; } u; u.s = v; return u.i;
}

// XLA-CPU tanh under legacy fast-math: Eigen/XLA rational approximation with
// FMA-contracted Horner chains. (R10-validated bit-level grading target.)
static __device__ __forceinline__ float xla_tanh_fma(float x) {
#pragma clang fp contract(off)
  const float kClamp = 7.90531110763549805f;
  float xc = fminf(fmaxf(x, -kClamp), kClamp);
  float x2 = xc * xc;
  float a;
  a = -2.76076847742355e-16f;                          // alpha_13
  a = __builtin_fmaf(a, x2, 2.00018790482477e-13f);    // alpha_11
  a = __builtin_fmaf(a, x2, -8.60467152213735e-11f);   // alpha_9
  a = __builtin_fmaf(a, x2, 5.12229709037114e-08f);    // alpha_7
  a = __builtin_fmaf(a, x2, 1.48572235717979e-05f);    // alpha_5
  a = __builtin_fmaf(a, x2, 6.37261928875436e-04f);    // alpha_3
  a = __builtin_fmaf(a, x2, 4.89352455891786e-03f);    // alpha_1
  float num = xc * a;
  float b;
  b = 1.19825839466702e-06f;                           // beta_6
  b = __builtin_fmaf(b, x2, 1.18534705686654e-04f);    // beta_4
  b = __builtin_fmaf(b, x2, 2.26843463243900e-03f);    // beta_2
  b = __builtin_fmaf(b, x2, 4.89352518554385e-03f);    // beta_0
  float r = num / b;                                   // IEEE div
  return (fabsf(x) < 0.0004f) ? x : r;
}

// ---------------- Phase 0: pack weights to bf16 (exact: |w|<=7) ----------------
__global__ __launch_bounds__(256) void pack_k(const int* __restrict__ Wr4,
                                              const int* __restrict__ Wi4,
                                              const float* __restrict__ Wo,
                                              short* __restrict__ WrB,
                                              short* __restrict__ WiB,
                                              short* __restrict__ WoB) {
  const int idx = blockIdx.x * 256 + threadIdx.x;  // grid 4096 -> 1,048,576
  {
    i32x4 v = *(const i32x4*)(Wr4 + (size_t)idx * 4);
    s16x4 o;
#pragma unroll
    for (int r = 0; r < 4; ++r) o[r] = f2bf((float)v[r]);
    *(s16x4*)(WrB + (size_t)idx * 4) = o;
  }
  if (idx < (H_ * F_ / 4)) {
    i32x4 v = *(const i32x4*)(Wi4 + (size_t)idx * 4);
    s16x4 o;
#pragma unroll
    for (int r = 0; r < 4; ++r) o[r] = f2bf((float)v[r]);
    *(s16x4*)(WiB + (size_t)idx * 4) = o;
  }
  if (idx < (V_ * H_ / 4)) {
    f32x4 f = *(const f32x4*)(Wo + (size_t)idx * 4);
    s16x4 o;
#pragma unroll
    for (int r = 0; r < 4; ++r) o[r] = f2bf(f[r]);
    *(s16x4*)(WoB + (size_t)idx * 4) = o;
  }
}

// ---------------- Phase 1: Oin[t][j][b] = clip(u_int @ Wi^T, int16) ----------------
__global__ __launch_bounds__(256) void in_gemm(const float* __restrict__ x,
                                               const short* __restrict__ WiB,
                                               short* __restrict__ Oin) {
  const int t  = blockIdx.x;
  const int jt = blockIdx.y;
  const int tid = threadIdx.x;
  const int l = tid & 63, w = tid >> 6;
  const int mh = w & 1, q = w >> 1;
  const int lr = l & 15, lc = l >> 4;
  const int brow = mh * 16 + lr;

  s16x8 af[4];
  const float* xp = x + ((size_t)brow * T_ + t) * F_;
#pragma unroll
  for (int kk = 0; kk < 4; ++kk) {
    f32x4 f0 = *(const f32x4*)(xp + kk * 32 + lc * 8);
    f32x4 f1 = *(const f32x4*)(xp + kk * 32 + lc * 8 + 4);
    s16x8 a;
#pragma unroll
    for (int c = 0; c < 4; ++c) a[c]     = f2bf(rintf(f0[c] * 7.0f));
#pragma unroll
    for (int c = 0; c < 4; ++c) a[4 + c] = f2bf(rintf(f1[c] * 7.0f));
    af[kk] = a;
  }
#pragma unroll
  for (int s = 0; s < 4; ++s) {
    const int j = jt * 128 + q * 64 + s * 16 + lr;
    f32x4 acc = {0.f, 0.f, 0.f, 0.f};
#pragma unroll
    for (int kk = 0; kk < 4; ++kk) {
      s16x8 b = *(const s16x8*)(WiB + (size_t)j * F_ + kk * 32 + lc * 8);
      acc = __builtin_amdgcn_mfma_f32_16x16x32_bf16(af[kk], b, acc, 0, 0, 0);
    }
    short* op = Oin + ((size_t)t * H_ + j) * B_ + mh * 16 + lc * 4;
    s16x4 ov;
#pragma unroll
    for (int r = 0; r < 4; ++r) ov[r] = (short)clampi16((int)acc[r]);
    *(s16x4*)op = ov;
  }
}

// ---------------- Phase 2: persistent recurrence (seq-flag sync, no counting barrier) ----------------
// R20 vs R19: the counting barrier (RMW arrival + tid0 8-load poll + fan-out
// sync, ~2.5-3.5us/step of serialized MALL RTTs) is replaced by single-writer
// SEQ FLAGS: producer bid does ONE relaxed atomic store flag[bid]=t+1 after
// its h-stores drain; at step t every wave's lane l polls flag[l] >= t in a
// divergent loop (one vector load per poll covers all 64 producers). oin load
// issued before the poll -> its RTT hides under it. Waves self-release (no
// fan-out sync). Flag store precedes the counted window -> counted vmcnt
// waits remain straggler-conservative. Numerics bit-identical to R10.
__global__ __launch_bounds__(256, 1) void recur_pers(const short* __restrict__ WrB,
                                                     const short* __restrict__ Oin,
                                                     const float* __restrict__ Sres,
                                                     const float* __restrict__ Sin,
                                                     short* __restrict__ Hb,
                                                     short* __restrict__ Hs,
                                                     int* __restrict__ flags) {
#pragma clang fp contract(off)
  __shared__ short hqt[32][36];
  __shared__ short hst[32][36];
  __shared__ f32x4 xch[2][2][64];   // [mh][uh][lane]

  const int tid = threadIdx.x;
  const int l = tid & 63, w = tid >> 6;
  const int mh = w & 1, nh = w >> 1;
  const int lr = l & 15, lc = l >> 4;
  const int jloc = nh * 16 + lr;
  const int jl = blockIdx.x * 32 + jloc;           // unit this wave FINALIZES
  const int b0 = mh * 16;
  const int jblk = blockIdx.x * 32;

  const float RC49 = 1.0f / 49.0f;
  const float sres = Sres[jl] * RC49;    // fast-math: x/49 -> x*(1/49)
  const float sinl = Sin[jl]  * RC49;

  // W fragments for BOTH unit halves, K-half nh only. 64 x s16x8, pinned.
  const short* wrow0 = WrB + (size_t)(jblk + lr) * H_      + nh * 1024 + lc * 8;
  const short* wrow1 = WrB + (size_t)(jblk + 16 + lr) * H_ + nh * 1024 + lc * 8;
  s16x8 wreg0[32], wreg1[32];
#pragma unroll
  for (int kk = 0; kk < 32; ++kk) {
    wreg0[kk] = *(const s16x8*)(wrow0 + kk * 32);
    asm volatile("" : "+v"(wreg0[kk]));
    wreg1[kk] = *(const s16x8*)(wrow1 + kk * 32);
    asm volatile("" : "+v"(wreg1[kk]));
  }

  // store-phase mapping: thread tid -> (bs, cs)
  const int bs = tid >> 3;          // 0..31
  const int cs = tid & 7;           // 0..7  (4-short chunk)

  asm volatile("s_waitcnt vmcnt(0)" ::: "memory");  // counted scheme starts at 0
  __builtin_amdgcn_sched_barrier(0);

  for (int t = 0; t < T_; ++t) {
    const short* hrow = Hb + (t & 1) * (B_ * H_)
                      + (size_t)(b0 + lr) * H_ + nh * 1024 + lc * 8;
    short* hout = Hb + ((t + 1) & 1) * (B_ * H_);

    // issue oin early: its RTT hides under the flag poll
    i32x2 oinr;
    {
      const short* op = Oin + ((size_t)t * H_ + jl) * B_ + b0 + lc * 4;
      asm volatile("global_load_dwordx2 %0, %1, off"
                   : "=v"(oinr) : "v"(op) : "memory");
    }

    // seq-flag poll: lane l watches producer l; divergent loop = wave-wide AND
    if (t != 0) {
      for (;;) {
        const int fv = __hip_atomic_load(&flags[l * 4], __ATOMIC_RELAXED,
                                         __HIP_MEMORY_SCOPE_AGENT);
        if (fv >= t) break;
        __builtin_amdgcn_s_sleep(1);
      }
    }

    i32x4 a[32];
#pragma unroll
    for (int i = 0; i < 32; ++i)
      asm volatile("global_load_dwordx4 %0, %1, off offset:%2 sc0 sc1"
                   : "=v"(a[i]) : "v"(hrow), "n"(i * 64) : "memory");

    f32x4 accE0 = {0.f, 0.f, 0.f, 0.f}, accO0 = {0.f, 0.f, 0.f, 0.f};
    f32x4 accE1 = {0.f, 0.f, 0.f, 0.f}, accO1 = {0.f, 0.f, 0.f, 0.f};

    asm volatile("s_waitcnt vmcnt(16)" ::: "memory");  // oin + first 16 landed
    __builtin_amdgcn_sched_barrier(0);
#pragma unroll
    for (int i = 0; i < 16; i += 2) {
      accE0 = __builtin_amdgcn_mfma_f32_16x16x32_bf16(as_s16x8(a[i]),     wreg0[i],     accE0, 0, 0, 0);
      accE1 = __builtin_amdgcn_mfma_f32_16x16x32_bf16(as_s16x8(a[i]),     wreg1[i],     accE1, 0, 0, 0);
      accO0 = __builtin_amdgcn_mfma_f32_16x16x32_bf16(as_s16x8(a[i + 1]), wreg0[i + 1], accO0, 0, 0, 0);
      accO1 = __builtin_amdgcn_mfma_f32_16x16x32_bf16(as_s16x8(a[i + 1]), wreg1[i + 1], accO1, 0, 0, 0);
    }
    asm volatile("s_waitcnt vmcnt(0)" ::: "memory");   // rest landed
    __builtin_amdgcn_sched_barrier(0);
#pragma unroll
    for (int i = 16; i < 32; i += 2) {
      accE0 = __builtin_amdgcn_mfma_f32_16x16x32_bf16(as_s16x8(a[i]),     wreg0[i],     accE0, 0, 0, 0);
      accE1 = __builtin_amdgcn_mfma_f32_16x16x32_bf16(as_s16x8(a[i]),     wreg1[i],     accE1, 0, 0, 0);
      accO0 = __builtin_amdgcn_mfma_f32_16x16x32_bf16(as_s16x8(a[i + 1]), wreg0[i + 1], accO0, 0, 0, 0);
      accO1 = __builtin_amdgcn_mfma_f32_16x16x32_bf16(as_s16x8(a[i + 1]), wreg1[i + 1], accO1, 0, 0, 0);
    }

    // merge even/odd chains (exact ints), exchange the half we don't finalize
    f32x4 own0, own1;
#pragma unroll
    for (int r = 0; r < 4; ++r) { own0[r] = accE0[r] + accO0[r]; own1[r] = accE1[r] + accO1[r]; }
    xch[mh][1 - nh][l] = (nh == 0) ? own1 : own0;
    __syncthreads();
    const f32x4 part = xch[mh][nh][l];
    const f32x4 mine = (nh == 0) ? own0 : own1;

    const s16x4 oin = as_s16x4(oinr);
#pragma unroll
    for (int r = 0; r < 4; ++r) {
      const int b = b0 + lc * 4 + r;
      const float resf = mine[r] + part[r];          // exact integer in f32
      const int   res  = clampi16((int)resf);
      const float t2   = (float)oin[r] * sinl;
      const float z    = __builtin_fmaf((float)res, sres, t2);
      const float h    = xla_tanh_fma(z);
      const float hc   = fminf(fmaxf(h, -1.0f), 1.0f);
      hqt[b][jloc] = f2bf(rintf(hc * 7.0f));
      hst[b][jloc] = f2bf(h);
    }

    __syncthreads();   // LDS tiles complete

    // coalesced stores: 8B per thread for h (MALL) and Hs (cached)
    {
      const i32x2 hqv = as_i32x2(*(const s16x4*)&hqt[bs][cs * 4]);
      const i32x2 hsv = as_i32x2(*(const s16x4*)&hst[bs][cs * 4]);
      short* hq_dst = hout + (size_t)bs * H_ + jblk + cs * 4;
      short* hs_dst = Hs + ((size_t)bs * T_ + t) * H_ + jblk + cs * 4;
      asm volatile("global_store_dwordx2 %0, %1, off sc0 sc1"
                   :: "v"(hq_dst), "v"(hqv) : "memory");
      asm volatile("global_store_dwordx2 %0, %1, off"
                   :: "v"(hs_dst), "v"(hsv) : "memory");
    }

    if (t != T_ - 1) {
      asm volatile("s_waitcnt vmcnt(0)" ::: "memory");  // both stores at MALL
      __syncthreads();                                   // all waves drained
      if (tid == 0)
        __hip_atomic_store(&flags[blockIdx.x * 4], t + 1,
                           __ATOMIC_RELAXED, __HIP_MEMORY_SCOPE_AGENT);
      // no fan-out sync: each wave self-releases via the t+1 poll
    }
  }
}

// ---------------- Phase 3: out(f32) = Hs(bf16) @ Wo(bf16)^T + bias ----------------
__global__ __launch_bounds__(256) void out_gemm(const unsigned short* __restrict__ Hs,
                                                const unsigned short* __restrict__ WoB,
                                                const float* __restrict__ bias,
                                                float* __restrict__ out) {
  const int tid = threadIdx.x;
  const int l = tid & 63, w = tid >> 6;
  const int m0 = blockIdx.x * 64 + w * 16;
  const int lr = l & 15, lc = l >> 4;

  f32x4 acc0 = {0.f, 0.f, 0.f, 0.f}, acc1 = {0.f, 0.f, 0.f, 0.f};
  const unsigned short* arow = Hs  + (size_t)(m0 + lr) * H_ + lc * 8;
  const unsigned short* bp0  = WoB + (size_t)lr * H_        + lc * 8;
  const unsigned short* bp1  = WoB + (size_t)(16 + lr) * H_ + lc * 8;
#pragma unroll 8
  for (int kk = 0; kk < 64; ++kk) {
    s16x8 a  = *(const s16x8*)(arow + kk * 32);
    s16x8 b0 = *(const s16x8*)(bp0  + kk * 32);
    s16x8 b1 = *(const s16x8*)(bp1  + kk * 32);
    acc0 = __builtin_amdgcn_mfma_f32_16x16x32_bf16(a, b0, acc0, 0, 0, 0);
    acc1 = __builtin_amdgcn_mfma_f32_16x16x32_bf16(a, b1, acc1, 0, 0, 0);
  }
#pragma unroll
  for (int r = 0; r < 4; ++r) {
    const int m = m0 + lc * 4 + r;
    out[(size_t)m * V_ + lr]      = acc0[r] + bias[lr];
    out[(size_t)m * V_ + 16 + lr] = acc1[r] + bias[16 + lr];
  }
}

// ---------------- launcher ----------------
extern "C" void kernel_launch(void* const* d_in, const int* in_sizes, int n_in,
                              void* d_out, int out_size, void* d_ws, size_t ws_size,
                              hipStream_t stream) {
  // sanity: dict-order inputs with expected element counts
  if (n_in != 7) return;
  const int exp_sz[7] = {B_ * T_ * F_, H_ * H_, H_ * F_, H_, H_, V_ * H_, V_};
  for (int i = 0; i < 7; ++i) if (in_sizes[i] != exp_sz[i]) return;

  const float* x    = (const float*)d_in[0];   // f32 (B,T,F)
  const int*   Wr4  = (const int*)d_in[1];     // int32 (H,H)
  const int*   Wi4  = (const int*)d_in[2];     // int32 (H,F)
  const float* Sres = (const float*)d_in[3];   // f32 (H)
  const float* Sin  = (const float*)d_in[4];   // f32 (H)
  const float* Wo   = (const float*)d_in[5];   // f32 (V,H)
  const float* Wob  = (const float*)d_in[6];   // f32 (V)
  float* out = (float*)d_out;
  char* ws = (char*)d_ws;

  // workspace layout (bytes)
  const size_t OFF_WRB = 0;                           //  8,388,608 (H*H bf16)
  const size_t OFF_WIB = 8388608;                     //    524,288 (H*F bf16)
  const size_t OFF_WOB = 8912896;                     //    131,072 (V*H bf16)
  const size_t OFF_OIN = 9043968;                     // 67,108,864 (int16 T*H*B)
  const size_t OFF_HS  = 76152832;                    // 67,108,864 (bf16 B*T*H)
  const size_t OFF_HB  = 143261696;                   //    262,144 (2 x B*H bf16 ping-pong)
  const size_t OFF_FLG = 143523840;                   //      1,024 (64 seq flags, 16B stride)
  const size_t NEED    = 143524864;
  if (ws_size < NEED) return;

  short* WrB = (short*)(ws + OFF_WRB);
  short* WiB = (short*)(ws + OFF_WIB);
  short* WoB = (short*)(ws + OFF_WOB);
  short* Oin = (short*)(ws + OFF_OIN);
  short* HsP = (short*)(ws + OFF_HS);
  short* Hb  = (short*)(ws + OFF_HB);
  int*   Flg = (int*)(ws + OFF_FLG);

  // h0 = 0 (ping buffer 0; buffer 1 fully written at t=0); flags = 0 each launch
  hipMemsetAsync(Hb, 0, B_ * H_ * 2, stream);
  hipMemsetAsync(Flg, 0, 1024, stream);

  pack_k<<<dim3(H_ * H_ / (4 * 256)), dim3(256), 0, stream>>>(Wr4, Wi4, Wo, WrB, WiB, WoB);
  in_gemm<<<dim3(T_, H_ / 128), dim3(256), 0, stream>>>(x, WiB, Oin);

  recur_pers<<<dim3(NBLK_), dim3(256), 0, stream>>>(WrB, Oin, Sres, Sin, Hb, HsP, Flg);

  out_gemm<<<dim3(256), dim3(256), 0, stream>>>((const unsigned short*)HsP,
                                                (const unsigned short*)WoB, Wob, out);
}